// Round 9
// baseline (14907.925 us; speedup 1.0000x reference)
//
#include <hip/hip_runtime.h>

#define B_ 32
#define T_ 2048
#define D_ 512
#define H_ 512
#define G4 2048
#define NREC 32    // recurrence blocks (1 wave each), each owns 16 hidden units
#define NWRK 192   // xproj worker blocks (1 wave each) in the fused dispatch

typedef short short8 __attribute__((ext_vector_type(8)));
typedef float floatv16 __attribute__((ext_vector_type(16)));
typedef float floatv4 __attribute__((ext_vector_type(4)));

static __device__ __forceinline__ unsigned short f2bf(float f) {
  union { float f; unsigned u; } v; v.f = f;
  unsigned u = v.u;
  u += 0x7fffu + ((u >> 16) & 1u);
  return (unsigned short)(u >> 16);
}
static __device__ __forceinline__ float bf2f(unsigned short h) {
  union { unsigned u; float f; } v; v.u = ((unsigned)h) << 16;
  return v.f;
}
static __device__ __forceinline__ float sigm(float x) { return 1.0f / (1.0f + __expf(-x)); }
static __device__ __forceinline__ float tanh_(float x) {
  float e = __expf(-2.0f * fabsf(x));
  float t = (1.0f - e) / (1.0f + e);
  return copysignf(t, x);
}

#define MFMA32(A, Bv, C) __builtin_amdgcn_mfma_f32_32x32x16_bf16((A), (Bv), (C), 0, 0, 0)

// ---------------- convert / prep kernel (round-0 verbatim) ----------------
__global__ __launch_bounds__(256) void cvt_kernel(
    const float* __restrict__ Wih, const float* __restrict__ Whh,
    const float* __restrict__ bih, const float* __restrict__ bhh,
    const float* __restrict__ h0, const float* __restrict__ c0,
    short* __restrict__ wih_hi, short* __restrict__ wih_lo, short* __restrict__ whh_hi,
    float* __restrict__ bias, short* __restrict__ hbuf0, float* __restrict__ cws) {
  int i = blockIdx.x * 256 + threadIdx.x;
  if (i < G4 * D_) {
    float w = Wih[i];
    unsigned short hi = f2bf(w);
    wih_hi[i] = (short)hi;
    wih_lo[i] = (short)f2bf(w - bf2f(hi));
    whh_hi[i] = (short)f2bf(Whh[i]);
  }
  if (i < G4) bias[i] = bih[i] + bhh[i];
  if (i < B_ * H_) { hbuf0[i] = (short)f2bf(h0[i]); cws[i] = c0[i]; }
}

// ---------------- phase A: x_proj GEMM for chunk 0 (round-0 verbatim) --------
__global__ __launch_bounds__(256, 1) void xproj_kernel(
    const float* __restrict__ input,
    const short* __restrict__ wih_hi, const short* __restrict__ wih_lo,
    const float* __restrict__ bias, float* __restrict__ xp, int t0, int TC) {
  __shared__ short xlo_lds[4 * 8192];
  const int tid = threadIdx.x;
  const int wv = tid >> 6, l = tid & 63;
  const int wid = blockIdx.x * 4 + wv;
  const int lt = wid >> 3, nb = wid & 7;
  const int t = t0 + lt;
  const int lb = l & 31, hb = l >> 5;
  const float* xrow = input + ((size_t)lb * T_ + t) * D_ + hb * 8;
  short* slo = xlo_lds + wv * 8192;
  short8 xhi[32];
#pragma unroll
  for (int kb = 0; kb < 32; ++kb) {
    floatv4 x0 = *(const floatv4*)(xrow + kb * 16);
    floatv4 x1 = *(const floatv4*)(xrow + kb * 16 + 4);
    float xs[8] = {x0[0], x0[1], x0[2], x0[3], x1[0], x1[1], x1[2], x1[3]};
    short8 hi, lo;
#pragma unroll
    for (int j = 0; j < 8; ++j) {
      unsigned short h = f2bf(xs[j]);
      hi[j] = (short)h;
      lo[j] = (short)f2bf(xs[j] - bf2f(h));
    }
    xhi[kb] = hi;
    *(short8*)(slo + (kb * 64 + l) * 8) = lo;
  }
  for (int nt = 0; nt < 8; ++nt) {
    const int n0 = nb * 256 + nt * 32;
    const short* whbase = wih_hi + (size_t)(n0 + lb) * D_ + hb * 8;
    const short* wlbase = wih_lo + (size_t)(n0 + lb) * D_ + hb * 8;
    floatv16 a0, a1;
#pragma unroll
    for (int i = 0; i < 16; ++i) { a0[i] = 0.0f; a1[i] = 0.0f; }
#pragma unroll
    for (int kb = 0; kb < 32; ++kb) {
      short8 whi = *(const short8*)(whbase + kb * 16);
      short8 wlo = *(const short8*)(wlbase + kb * 16);
      short8 xl = *(const short8*)(slo + (kb * 64 + l) * 8);
      a0 = MFMA32(whi, xhi[kb], a0);      // hi * hi
      a1 = MFMA32(whi, xl, a1);           // Whi * xlo
      a1 = MFMA32(wlo, xhi[kb], a1);      // Wlo * xhi
    }
#pragma unroll
    for (int r = 0; r < 16; ++r) {
      int row = (r & 3) + 8 * (r >> 2) + 4 * hb;
      int n = n0 + row;
      xp[((size_t)lt * G4 + n) * B_ + lb] = a0[r] + a1[r] + bias[n];
    }
  }
}

// ---------------- fused per-chunk kernel ----------------
// blocks 0..31   : recurrence, chunk [t0, t0+TC) reading xpc (written by the
//                  PREVIOUS dispatch — stream order guarantees).
//                  32 waves x 16 hidden units each: two 32-row MFMA blocks
//                  (Wf0/Wf1, 256 VGPRs) sharing the same h B-fragments.
//                  Sync protocol = round-0 proven form (per-wave release-store
//                  flag, per-iteration ACQUIRE poll), now over 32 participants.
// blocks 32..223 : xproj workers producing chunk t0+TC into xpn (if doNext).
__global__ __launch_bounds__(64, 1) void fused_step(
    const float* __restrict__ input,
    const short* __restrict__ wih_hi, const short* __restrict__ wih_lo,
    const float* __restrict__ bias, const short* __restrict__ whh,
    short* __restrict__ hbuf, float* __restrict__ cws, int* __restrict__ flags,
    const float* __restrict__ xpc, float* __restrict__ xpn,
    float* __restrict__ out, int t0, int TC, int writeOut, int doNext) {
  __shared__ short slo[16384];  // worker staging (32KB, exact 1-wave footprint)
  const int l = threadIdx.x;
  const int lb = l & 31, hb = l >> 5;

  if (blockIdx.x < NREC) {
    // ---------------- recurrence role ----------------
    const int w = blockIdx.x;                            // 0..31
    const int ngl0 = (lb >> 3) * H_ + w * 16 + (lb & 7); // blk0 rows in W_hh
    const int ngl1 = ngl0 + 8;                           // blk1 rows
    short8 Wf0[32], Wf1[32];
#pragma unroll
    for (int kb = 0; kb < 32; ++kb) {
      Wf0[kb] = *(const short8*)(whh + (size_t)ngl0 * H_ + kb * 16 + hb * 8);
      Wf1[kb] = *(const short8*)(whh + (size_t)ngl1 * H_ + kb * 16 + hb * 8);
    }
    float c8[8], h8[8];
#pragma unroll
    for (int q = 0; q < 8; ++q)
      c8[q] = cws[lb * H_ + w * 16 + (q >> 2) * 8 + 4 * hb + (q & 3)];

    for (int t = t0; t < t0 + TC; ++t) {
      // prefetch x_proj for this step (independent of h, hides under the wait)
      const float* xpt = xpc + (size_t)(t - t0) * G4 * B_;
      float xpv[32];
#pragma unroll
      for (int g = 0; g < 4; ++g)
#pragma unroll
        for (int q = 0; q < 8; ++q)
          xpv[g * 8 + q] =
              xpt[(size_t)(g * H_ + w * 16 + (q >> 2) * 8 + 4 * hb + (q & 3)) * B_ + lb];

      if (t > 0) {  // wait for all 32 producers to have published h_t
        int v;
        do {
          v = __hip_atomic_load(flags + (l & 31) * 16, __ATOMIC_ACQUIRE,
                                __HIP_MEMORY_SCOPE_AGENT);
        } while (!__all(v >= t));
      }

      const short* hsrc = hbuf + (t & 1) * (B_ * H_) + lb * H_ + hb * 8;
      floatv16 D0a, D1a, D0b, D1b;
#pragma unroll
      for (int i = 0; i < 16; ++i) { D0a[i] = 0.0f; D1a[i] = 0.0f; D0b[i] = 0.0f; D1b[i] = 0.0f; }
#pragma unroll
      for (int kb = 0; kb < 32; kb += 2) {  // 4 independent MFMA chains, shared B
        short8 hf0 = *(const short8*)(hsrc + kb * 16);
        short8 hf1 = *(const short8*)(hsrc + kb * 16 + 16);
        D0a = MFMA32(Wf0[kb], hf0, D0a);
        D1a = MFMA32(Wf0[kb + 1], hf1, D1a);
        D0b = MFMA32(Wf1[kb], hf0, D0b);
        D1b = MFMA32(Wf1[kb + 1], hf1, D1b);
      }

      union { unsigned short s[4]; unsigned long long u; } pk0, pk1;
#pragma unroll
      for (int q = 0; q < 4; ++q) {
        // blk0: units w*16 + 4*hb + q
        float gi = D0a[q] + D1a[q] + xpv[q];
        float gf = D0a[4 + q] + D1a[4 + q] + xpv[8 + q];
        float gg = D0a[8 + q] + D1a[8 + q] + xpv[16 + q];
        float go = D0a[12 + q] + D1a[12 + q] + xpv[24 + q];
        float iv = sigm(gi), fv = sigm(gf), gv = tanh_(gg), ov = sigm(go);
        c8[q] = fv * c8[q] + iv * gv;
        h8[q] = ov * tanh_(c8[q]);
        pk0.s[q] = f2bf(h8[q]);
        // blk1: units w*16 + 8 + 4*hb + q
        float gi1 = D0b[q] + D1b[q] + xpv[4 + q];
        float gf1 = D0b[4 + q] + D1b[4 + q] + xpv[12 + q];
        float gg1 = D0b[8 + q] + D1b[8 + q] + xpv[20 + q];
        float go1 = D0b[12 + q] + D1b[12 + q] + xpv[28 + q];
        float iv1 = sigm(gi1), fv1 = sigm(gf1), gv1 = tanh_(gg1), ov1 = sigm(go1);
        c8[4 + q] = fv1 * c8[4 + q] + iv1 * gv1;
        h8[4 + q] = ov1 * tanh_(c8[4 + q]);
        pk1.s[q] = f2bf(h8[4 + q]);
      }
      short* hdb = hbuf + ((t + 1) & 1) * (B_ * H_) + lb * H_ + w * 16 + 4 * hb;
      __hip_atomic_store((unsigned long long*)hdb, pk0.u, __ATOMIC_RELAXED,
                         __HIP_MEMORY_SCOPE_AGENT);
      __hip_atomic_store((unsigned long long*)(hdb + 8), pk1.u, __ATOMIC_RELAXED,
                         __HIP_MEMORY_SCOPE_AGENT);
      if (l == 0)
        __hip_atomic_store(flags + w * 16, t + 1, __ATOMIC_RELEASE, __HIP_MEMORY_SCOPE_AGENT);
    }

#pragma unroll
    for (int q = 0; q < 8; ++q)
      cws[lb * H_ + w * 16 + (q >> 2) * 8 + 4 * hb + (q & 3)] = c8[q];
    if (writeOut) {
#pragma unroll
      for (int q = 0; q < 8; ++q) {
        int u = w * 16 + (q >> 2) * 8 + 4 * hb + (q & 3);
        out[lb * H_ + u] = h8[q];                 // final h
        out[B_ * H_ + lb * H_ + u] = c8[q];       // final c
      }
    }
  } else if (doNext) {
    // ---------------- xproj worker role: produce chunk t0+TC into xpn -------
    const int wkr = blockIdx.x - NREC;
    const int t0n = t0 + TC;
    for (int j = wkr; j < TC * 8; j += NWRK) {
      const int lt = j >> 3, nb = j & 7;
      const int t = t0n + lt;
      const float* xrow = input + ((size_t)lb * T_ + t) * D_ + hb * 8;
      short8 xhi[32];
#pragma unroll
      for (int kb = 0; kb < 32; ++kb) {
        floatv4 x0 = *(const floatv4*)(xrow + kb * 16);
        floatv4 x1 = *(const floatv4*)(xrow + kb * 16 + 4);
        float xs[8] = {x0[0], x0[1], x0[2], x0[3], x1[0], x1[1], x1[2], x1[3]};
        short8 hi, lo;
#pragma unroll
        for (int jj = 0; jj < 8; ++jj) {
          unsigned short h = f2bf(xs[jj]);
          hi[jj] = (short)h;
          lo[jj] = (short)f2bf(xs[jj] - bf2f(h));
        }
        xhi[kb] = hi;
        *(short8*)(slo + (kb * 64 + l) * 8) = lo;
      }
      for (int nt = 0; nt < 8; ++nt) {
        const int n0 = nb * 256 + nt * 32;
        const short* whbase = wih_hi + (size_t)(n0 + lb) * D_ + hb * 8;
        const short* wlbase = wih_lo + (size_t)(n0 + lb) * D_ + hb * 8;
        floatv16 a0, a1;
#pragma unroll
        for (int i = 0; i < 16; ++i) { a0[i] = 0.0f; a1[i] = 0.0f; }
#pragma unroll
        for (int kb = 0; kb < 32; ++kb) {
          short8 whi = *(const short8*)(whbase + kb * 16);
          short8 wlo = *(const short8*)(wlbase + kb * 16);
          short8 xl = *(const short8*)(slo + (kb * 64 + l) * 8);
          a0 = MFMA32(whi, xhi[kb], a0);      // hi * hi
          a1 = MFMA32(whi, xl, a1);           // Whi * xlo
          a1 = MFMA32(wlo, xhi[kb], a1);      // Wlo * xhi
        }
#pragma unroll
        for (int r = 0; r < 16; ++r) {
          int row = (r & 3) + 8 * (r >> 2) + 4 * hb;
          int n = n0 + row;
          xpn[((size_t)lt * G4 + n) * B_ + lb] = a0[r] + a1[r] + bias[n];
        }
      }
    }
  }
}

extern "C" void kernel_launch(void* const* d_in, const int* in_sizes, int n_in,
                              void* d_out, int out_size, void* d_ws, size_t ws_size,
                              hipStream_t stream) {
  (void)in_sizes; (void)n_in; (void)out_size;
  const float* input = (const float*)d_in[0];
  const float* h0 = (const float*)d_in[1];
  const float* c0 = (const float*)d_in[2];
  const float* Wih = (const float*)d_in[3];
  const float* Whh = (const float*)d_in[4];
  const float* bih = (const float*)d_in[5];
  const float* bhh = (const float*)d_in[6];

  char* ws = (char*)d_ws;
  short* wih_hi = (short*)(ws);
  short* wih_lo = (short*)(ws + (2ull << 20));
  short* whh_hi = (short*)(ws + (4ull << 20));
  float* bias = (float*)(ws + (6ull << 20));
  short* hbuf = (short*)(ws + (6ull << 20) + 65536);
  float* cws = (float*)(ws + (6ull << 20) + 131072);
  int* flags = (int*)(ws + (6ull << 20) + 196608);

  // chunk size: double-buffered xp needs 8MB + 2*TC*256KB <= ws_size
  int TC = 32;
  while (TC < 256 && (8ull << 20) + (size_t)(TC * 2) * (G4 * B_ * 4) <= ws_size) TC <<= 1;
  const int nch = T_ / TC;
  float* xpA = (float*)(ws + (8ull << 20));
  float* xpB = xpA + (size_t)TC * G4 * B_;

  hipMemsetAsync(flags, 0, 4096, stream);
  cvt_kernel<<<dim3((G4 * D_ + 255) / 256), dim3(256), 0, stream>>>(
      Wih, Whh, bih, bhh, h0, c0, wih_hi, wih_lo, whh_hi, bias, hbuf, cws);
  // chunk 0's xp via the standalone (full-width) xproj
  xproj_kernel<<<dim3(TC * 2), dim3(256), 0, stream>>>(input, wih_hi, wih_lo, bias,
                                                       xpA, 0, TC);
  for (int k = 0; k < nch; ++k) {
    float* cur = (k & 1) ? xpB : xpA;
    float* nxt = (k & 1) ? xpA : xpB;
    fused_step<<<dim3(NREC + NWRK), dim3(64), 0, stream>>>(
        input, wih_hi, wih_lo, bias, whh_hi, hbuf, cws, flags, cur, nxt,
        (float*)d_out, k * TC, TC, (k == nch - 1) ? 1 : 0, (k < nch - 1) ? 1 : 0);
  }
}

// Round 10
// 14475.098 us; speedup vs baseline: 1.0299x; 1.0299x over previous
//
#include <hip/hip_runtime.h>

#define B_ 32
#define T_ 2048
#define D_ 512
#define H_ 512
#define G4 2048
#define NREC 64    // recurrence blocks (1 wave each), each owns 8 hidden units
#define NWRK 192   // xproj worker blocks (1 wave each) in the fused dispatch

typedef short short8 __attribute__((ext_vector_type(8)));
typedef float floatv16 __attribute__((ext_vector_type(16)));
typedef float floatv4 __attribute__((ext_vector_type(4)));
typedef unsigned long long u64;

static __device__ __forceinline__ unsigned short f2bf(float f) {
  union { float f; unsigned u; } v; v.f = f;
  unsigned u = v.u;
  u += 0x7fffu + ((u >> 16) & 1u);
  return (unsigned short)(u >> 16);
}
static __device__ __forceinline__ float bf2f(unsigned short h) {
  union { unsigned u; float f; } v; v.u = ((unsigned)h) << 16;
  return v.f;
}
static __device__ __forceinline__ float sigm(float x) { return 1.0f / (1.0f + __expf(-x)); }
static __device__ __forceinline__ float tanh_(float x) {
  float e = __expf(-2.0f * fabsf(x));
  float t = (1.0f - e) / (1.0f + e);
  return copysignf(t, x);
}

#define MFMA32(A, Bv, C) __builtin_amdgcn_mfma_f32_32x32x16_bf16((A), (Bv), (C), 0, 0, 0)

// ---------------- convert / prep kernel (round-0 verbatim) ----------------
__global__ __launch_bounds__(256) void cvt_kernel(
    const float* __restrict__ Wih, const float* __restrict__ Whh,
    const float* __restrict__ bih, const float* __restrict__ bhh,
    const float* __restrict__ h0, const float* __restrict__ c0,
    short* __restrict__ wih_hi, short* __restrict__ wih_lo, short* __restrict__ whh_hi,
    float* __restrict__ bias, short* __restrict__ hbuf0, float* __restrict__ cws) {
  int i = blockIdx.x * 256 + threadIdx.x;
  if (i < G4 * D_) {
    float w = Wih[i];
    unsigned short hi = f2bf(w);
    wih_hi[i] = (short)hi;
    wih_lo[i] = (short)f2bf(w - bf2f(hi));
    whh_hi[i] = (short)f2bf(Whh[i]);
  }
  if (i < G4) bias[i] = bih[i] + bhh[i];
  if (i < B_ * H_) { hbuf0[i] = (short)f2bf(h0[i]); cws[i] = c0[i]; }
}

// ---------------- phase A: x_proj GEMM for chunk 0 (round-0 verbatim) --------
__global__ __launch_bounds__(256, 1) void xproj_kernel(
    const float* __restrict__ input,
    const short* __restrict__ wih_hi, const short* __restrict__ wih_lo,
    const float* __restrict__ bias, float* __restrict__ xp, int t0, int TC) {
  __shared__ short xlo_lds[4 * 8192];
  const int tid = threadIdx.x;
  const int wv = tid >> 6, l = tid & 63;
  const int wid = blockIdx.x * 4 + wv;
  const int lt = wid >> 3, nb = wid & 7;
  const int t = t0 + lt;
  const int lb = l & 31, hb = l >> 5;
  const float* xrow = input + ((size_t)lb * T_ + t) * D_ + hb * 8;
  short* slo = xlo_lds + wv * 8192;
  short8 xhi[32];
#pragma unroll
  for (int kb = 0; kb < 32; ++kb) {
    floatv4 x0 = *(const floatv4*)(xrow + kb * 16);
    floatv4 x1 = *(const floatv4*)(xrow + kb * 16 + 4);
    float xs[8] = {x0[0], x0[1], x0[2], x0[3], x1[0], x1[1], x1[2], x1[3]};
    short8 hi, lo;
#pragma unroll
    for (int j = 0; j < 8; ++j) {
      unsigned short h = f2bf(xs[j]);
      hi[j] = (short)h;
      lo[j] = (short)f2bf(xs[j] - bf2f(h));
    }
    xhi[kb] = hi;
    *(short8*)(slo + (kb * 64 + l) * 8) = lo;
  }
  for (int nt = 0; nt < 8; ++nt) {
    const int n0 = nb * 256 + nt * 32;
    const short* whbase = wih_hi + (size_t)(n0 + lb) * D_ + hb * 8;
    const short* wlbase = wih_lo + (size_t)(n0 + lb) * D_ + hb * 8;
    floatv16 a0, a1;
#pragma unroll
    for (int i = 0; i < 16; ++i) { a0[i] = 0.0f; a1[i] = 0.0f; }
#pragma unroll
    for (int kb = 0; kb < 32; ++kb) {
      short8 whi = *(const short8*)(whbase + kb * 16);
      short8 wlo = *(const short8*)(wlbase + kb * 16);
      short8 xl = *(const short8*)(slo + (kb * 64 + l) * 8);
      a0 = MFMA32(whi, xhi[kb], a0);      // hi * hi
      a1 = MFMA32(whi, xl, a1);           // Whi * xlo
      a1 = MFMA32(wlo, xhi[kb], a1);      // Wlo * xhi
    }
#pragma unroll
    for (int r = 0; r < 16; ++r) {
      int row = (r & 3) + 8 * (r >> 2) + 4 * hb;
      int n = n0 + row;
      xp[((size_t)lt * G4 + n) * B_ + lb] = a0[r] + a1[r] + bias[n];
    }
  }
}

// ---------------- fused per-chunk kernel ----------------
// Round-7 structure; ONLY the hot-loop memory orderings changed:
//  - publish: relaxed h stores -> explicit s_waitcnt vmcnt(0) (drain only,
//    no L2 writeback) -> RELAXED flag store   (was: RELEASE = wb + drain)
//  - poll: RELAXED loads, no per-iteration invalidate; compiler barrier after
//  - h fragment loads: atomic RELAXED 8B agent loads (bypass stale caches by
//    construction, replacing the invalidate-then-plain-load scheme)
// Ordering: flag visible at coherence point => h stores ack'd there (producer
// vmcnt drain orders them); consumer bypass-loads issued after detect see them.
__global__ __launch_bounds__(64, 1) void fused_step(
    const float* __restrict__ input,
    const short* __restrict__ wih_hi, const short* __restrict__ wih_lo,
    const float* __restrict__ bias, const short* __restrict__ whh,
    short* __restrict__ hbuf, float* __restrict__ cws, int* __restrict__ flags,
    const float* __restrict__ xpc, float* __restrict__ xpn,
    float* __restrict__ out, int t0, int TC, int writeOut, int doNext) {
  __shared__ short slo[16384];  // worker staging (32KB, exact 1-wave footprint)
  const int l = threadIdx.x;
  const int lb = l & 31, hb = l >> 5;

  if (blockIdx.x < NREC) {
    // ---------------- recurrence role ----------------
    const int w = blockIdx.x;
    const int ngl = (lb >> 3) * H_ + w * 8 + (lb & 7);  // row in W_hh [2048x512]
    short8 Wf[32];
#pragma unroll
    for (int kb = 0; kb < 32; ++kb)
      Wf[kb] = *(const short8*)(whh + (size_t)ngl * H_ + kb * 16 + hb * 8);
    float c4[4], h4[4];
#pragma unroll
    for (int q = 0; q < 4; ++q) c4[q] = cws[lb * H_ + w * 8 + 4 * hb + q];

    for (int t = t0; t < t0 + TC; ++t) {
      // prefetch x_proj for this step (independent of h, hides under the wait)
      const float* xpt = xpc + (size_t)(t - t0) * G4 * B_;
      float xpv[16];
#pragma unroll
      for (int g = 0; g < 4; ++g)
#pragma unroll
        for (int q = 0; q < 4; ++q)
          xpv[g * 4 + q] = xpt[(size_t)(g * H_ + w * 8 + 4 * hb + q) * B_ + lb];

      if (t > 0) {  // wait for all 64 producers: relaxed poll, no cache-inv
        int v;
        do {
          v = __hip_atomic_load(flags + l * 16, __ATOMIC_RELAXED, __HIP_MEMORY_SCOPE_AGENT);
        } while (!__all(v >= t));
        asm volatile("" ::: "memory");  // compile-time order only
      }

      const short* hsrc = hbuf + (t & 1) * (B_ * H_) + lb * H_ + hb * 8;
      floatv16 D0, D1;
#pragma unroll
      for (int i = 0; i < 16; ++i) { D0[i] = 0.0f; D1[i] = 0.0f; }
#pragma unroll
      for (int kb = 0; kb < 32; kb += 2) {  // 2 independent MFMA chains
        union { u64 d[2]; short8 s8; } f0, f1;
        const u64* p0 = (const u64*)(hsrc + kb * 16);
        const u64* p1 = (const u64*)(hsrc + kb * 16 + 16);
        f0.d[0] = __hip_atomic_load(p0, __ATOMIC_RELAXED, __HIP_MEMORY_SCOPE_AGENT);
        f0.d[1] = __hip_atomic_load(p0 + 1, __ATOMIC_RELAXED, __HIP_MEMORY_SCOPE_AGENT);
        f1.d[0] = __hip_atomic_load(p1, __ATOMIC_RELAXED, __HIP_MEMORY_SCOPE_AGENT);
        f1.d[1] = __hip_atomic_load(p1 + 1, __ATOMIC_RELAXED, __HIP_MEMORY_SCOPE_AGENT);
        D0 = MFMA32(Wf[kb], f0.s8, D0);
        D1 = MFMA32(Wf[kb + 1], f1.s8, D1);
      }

      union { unsigned short s[4]; u64 u; } pk;
#pragma unroll
      for (int q = 0; q < 4; ++q) {
        float gi = D0[q] + D1[q] + xpv[q];
        float gf = D0[4 + q] + D1[4 + q] + xpv[4 + q];
        float gg = D0[8 + q] + D1[8 + q] + xpv[8 + q];
        float go = D0[12 + q] + D1[12 + q] + xpv[12 + q];
        float iv = sigm(gi), fv = sigm(gf), gv = tanh_(gg), ov = sigm(go);
        c4[q] = fv * c4[q] + iv * gv;
        h4[q] = ov * tanh_(c4[q]);
        pk.s[q] = f2bf(h4[q]);
      }
      u64* hdst = (u64*)(hbuf + ((t + 1) & 1) * (B_ * H_) + lb * H_ + w * 8 + 4 * hb);
      __hip_atomic_store(hdst, pk.u, __ATOMIC_RELAXED, __HIP_MEMORY_SCOPE_AGENT);
      // drain this wave's h store to the coherence point (no L2 writeback op),
      // then publish with a plain relaxed store.
      asm volatile("s_waitcnt vmcnt(0)" ::: "memory");
      if (l == 0)
        __hip_atomic_store(flags + w * 16, t + 1, __ATOMIC_RELAXED, __HIP_MEMORY_SCOPE_AGENT);
    }

#pragma unroll
    for (int q = 0; q < 4; ++q) cws[lb * H_ + w * 8 + 4 * hb + q] = c4[q];
    if (writeOut) {
#pragma unroll
      for (int q = 0; q < 4; ++q) {
        out[lb * H_ + w * 8 + 4 * hb + q] = h4[q];                 // final h
        out[B_ * H_ + lb * H_ + w * 8 + 4 * hb + q] = c4[q];       // final c
      }
    }
  } else if (doNext) {
    // ---------------- xproj worker role: produce chunk t0+TC into xpn -------
    const int wkr = blockIdx.x - NREC;
    const int t0n = t0 + TC;
    for (int j = wkr; j < TC * 8; j += NWRK) {
      const int lt = j >> 3, nb = j & 7;
      const int t = t0n + lt;
      const float* xrow = input + ((size_t)lb * T_ + t) * D_ + hb * 8;
      short8 xhi[32];
#pragma unroll
      for (int kb = 0; kb < 32; ++kb) {
        floatv4 x0 = *(const floatv4*)(xrow + kb * 16);
        floatv4 x1 = *(const floatv4*)(xrow + kb * 16 + 4);
        float xs[8] = {x0[0], x0[1], x0[2], x0[3], x1[0], x1[1], x1[2], x1[3]};
        short8 hi, lo;
#pragma unroll
        for (int jj = 0; jj < 8; ++jj) {
          unsigned short h = f2bf(xs[jj]);
          hi[jj] = (short)h;
          lo[jj] = (short)f2bf(xs[jj] - bf2f(h));
        }
        xhi[kb] = hi;
        *(short8*)(slo + (kb * 64 + l) * 8) = lo;
      }
      for (int nt = 0; nt < 8; ++nt) {
        const int n0 = nb * 256 + nt * 32;
        const short* whbase = wih_hi + (size_t)(n0 + lb) * D_ + hb * 8;
        const short* wlbase = wih_lo + (size_t)(n0 + lb) * D_ + hb * 8;
        floatv16 a0, a1;
#pragma unroll
        for (int i = 0; i < 16; ++i) { a0[i] = 0.0f; a1[i] = 0.0f; }
#pragma unroll
        for (int kb = 0; kb < 32; ++kb) {
          short8 whi = *(const short8*)(whbase + kb * 16);
          short8 wlo = *(const short8*)(wlbase + kb * 16);
          short8 xl = *(const short8*)(slo + (kb * 64 + l) * 8);
          a0 = MFMA32(whi, xhi[kb], a0);      // hi * hi
          a1 = MFMA32(whi, xl, a1);           // Whi * xlo
          a1 = MFMA32(wlo, xhi[kb], a1);      // Wlo * xhi
        }
#pragma unroll
        for (int r = 0; r < 16; ++r) {
          int row = (r & 3) + 8 * (r >> 2) + 4 * hb;
          int n = n0 + row;
          xpn[((size_t)lt * G4 + n) * B_ + lb] = a0[r] + a1[r] + bias[n];
        }
      }
    }
  }
}

extern "C" void kernel_launch(void* const* d_in, const int* in_sizes, int n_in,
                              void* d_out, int out_size, void* d_ws, size_t ws_size,
                              hipStream_t stream) {
  (void)in_sizes; (void)n_in; (void)out_size;
  const float* input = (const float*)d_in[0];
  const float* h0 = (const float*)d_in[1];
  const float* c0 = (const float*)d_in[2];
  const float* Wih = (const float*)d_in[3];
  const float* Whh = (const float*)d_in[4];
  const float* bih = (const float*)d_in[5];
  const float* bhh = (const float*)d_in[6];

  char* ws = (char*)d_ws;
  short* wih_hi = (short*)(ws);
  short* wih_lo = (short*)(ws + (2ull << 20));
  short* whh_hi = (short*)(ws + (4ull << 20));
  float* bias = (float*)(ws + (6ull << 20));
  short* hbuf = (short*)(ws + (6ull << 20) + 65536);
  float* cws = (float*)(ws + (6ull << 20) + 131072);
  int* flags = (int*)(ws + (6ull << 20) + 196608);

  // chunk size: double-buffered xp needs 8MB + 2*TC*256KB <= ws_size
  int TC = 32;
  while (TC < 256 && (8ull << 20) + (size_t)(TC * 2) * (G4 * B_ * 4) <= ws_size) TC <<= 1;
  const int nch = T_ / TC;
  float* xpA = (float*)(ws + (8ull << 20));
  float* xpB = xpA + (size_t)TC * G4 * B_;

  hipMemsetAsync(flags, 0, 4096, stream);
  cvt_kernel<<<dim3((G4 * D_ + 255) / 256), dim3(256), 0, stream>>>(
      Wih, Whh, bih, bhh, h0, c0, wih_hi, wih_lo, whh_hi, bias, hbuf, cws);
  // chunk 0's xp via the standalone (full-width) xproj
  xproj_kernel<<<dim3(TC * 2), dim3(256), 0, stream>>>(input, wih_hi, wih_lo, bias,
                                                       xpA, 0, TC);
  for (int k = 0; k < nch; ++k) {
    float* cur = (k & 1) ? xpB : xpA;
    float* nxt = (k & 1) ? xpA : xpB;
    fused_step<<<dim3(NREC + NWRK), dim3(64), 0, stream>>>(
        input, wih_hi, wih_lo, bias, whh_hi, hbuf, cws, flags, cur, nxt,
        (float*)d_out, k * TC, TC, (k == nch - 1) ? 1 : 0, (k < nch - 1) ? 1 : 0);
  }
}